// Round 8
// baseline (937.307 us; speedup 1.0000x reference)
//
#include <hip/hip_runtime.h>
#include <stdint.h>

// SimpleTrixFFN round 8: revert to the r2-proven m97 structure (BK=64,
// 2-barrier, 128x128, 4 waves, 2 blocks/CU) for all GEMMs — every schedule
// redesign since lost to it. Single new lever: XCD-aware flat-grid decode
// (T1) so panel-sharing blocks co-reside per XCD L2 (up: n-partitioned,
// down: z-per-XCD-pair + B-panel-resident), fixing the measured 1.07/1.1 GB
// over-fetch.

typedef __attribute__((ext_vector_type(8))) __bf16 bf16x8;
typedef __attribute__((ext_vector_type(4))) float f32x4;

__device__ __forceinline__ unsigned short f2bf(float f) {
  union { float f; unsigned int u; } c; c.f = f;
  unsigned int u = c.u;
  u += 0x7FFFu + ((u >> 16) & 1u);   // round-to-nearest-even
  return (unsigned short)(u >> 16);
}

__device__ __forceinline__ float gelu_fast(float x) {
  // x * sigmoid(1.5957691*(x + 0.044715 x^3)) == tanh-form gelu, |err|<=2e-4
  float x2 = x * x;
  float p = __builtin_fmaf(0.044715f * x2, x, x);
  float e = __expf(-1.5957691216057308f * p);
  return x / (1.0f + e);
}

__device__ __forceinline__ void gload16(const void* g, void* l) {
  __builtin_amdgcn_global_load_lds((const __attribute__((address_space(1))) void*)g,
                                   (__attribute__((address_space(3))) void*)l,
                                   16, 0, 0);
}

// ---------------- conversion kernels ----------------
__global__ void conv_bf16(const float* __restrict__ in, unsigned short* __restrict__ out, int n4) {
  int i = blockIdx.x * blockDim.x + threadIdx.x;
  if (i >= n4) return;
  float4 v = reinterpret_cast<const float4*>(in)[i];
  ushort4 o;
  o.x = f2bf(v.x); o.y = f2bf(v.y); o.z = f2bf(v.z); o.w = f2bf(v.w);
  reinterpret_cast<ushort4*>(out)[i] = o;
}

// W_down (8,1024,4096)[t][d][h] -> bf16 (1024, 32768)[d][t*4096+h]
__global__ void conv_wdn(const float* __restrict__ in, unsigned short* __restrict__ out) {
  int i = blockIdx.x * blockDim.x + threadIdx.x;
  int idx = i * 4;
  int h = idx & 4095;
  int d = (idx >> 12) & 1023;
  int t = idx >> 22;
  float4 v = *reinterpret_cast<const float4*>(in + (size_t)(t * 1024 + d) * 4096 + h);
  ushort4 o;
  o.x = f2bf(v.x); o.y = f2bf(v.y); o.z = f2bf(v.z); o.w = f2bf(v.w);
  *reinterpret_cast<ushort4*>(out + (size_t)d * 32768 + t * 4096 + h) = o;
}

// W_cls (1000,1024) -> padded bf16 (1024,1024)
__global__ void conv_wcls(const float* __restrict__ in, unsigned short* __restrict__ out) {
  int i = blockIdx.x * blockDim.x + threadIdx.x;
  int idx = i * 4;
  int row = idx >> 10;
  float4 v = make_float4(0.f, 0.f, 0.f, 0.f);
  if (row < 1000) v = *reinterpret_cast<const float4*>(in + row * 1024 + (idx & 1023));
  ushort4 o;
  o.x = f2bf(v.x); o.y = f2bf(v.y); o.z = f2bf(v.z); o.w = f2bf(v.w);
  reinterpret_cast<ushort4*>(out)[i] = o;
}

// ---------------- routing ----------------
__global__ void score_init(const float* __restrict__ x, const float* __restrict__ sig,
                           const float* __restrict__ b_down,
                           float* __restrict__ w_ws, float* __restrict__ out_init,
                           float* __restrict__ w_out, float* __restrict__ idx_out) {
  const int b = blockIdx.x;
  const int tid = threadIdx.x;
  const int lane = tid & 63;
  const int wave = tid >> 6;
  const float* xr = x + (size_t)b * 1024;

  float p[8];
  #pragma unroll
  for (int t = 0; t < 8; ++t) p[t] = 0.f;
  for (int k = tid; k < 1024; k += 256) {
    float xv = xr[k];
    #pragma unroll
    for (int t = 0; t < 8; ++t) p[t] += xv * sig[t * 1024 + k];
  }
  #pragma unroll
  for (int t = 0; t < 8; ++t) {
    #pragma unroll
    for (int off = 32; off > 0; off >>= 1) p[t] += __shfl_down(p[t], off);
  }
  __shared__ float red[4][8];
  __shared__ float wsh[8];
  if (lane == 0) {
    #pragma unroll
    for (int t = 0; t < 8; ++t) red[wave][t] = p[t];
  }
  __syncthreads();
  if (tid == 0) {
    float s[8];
    #pragma unroll
    for (int t = 0; t < 8; ++t) s[t] = red[0][t] + red[1][t] + red[2][t] + red[3][t];
    int amax = 0; float mx = s[0];
    #pragma unroll
    for (int t = 1; t < 8; ++t) { if (s[t] > mx) { mx = s[t]; amax = t; } }
    float e[8], sum = 0.f;
    #pragma unroll
    for (int t = 0; t < 8; ++t) { e[t] = expf((s[t] - mx) * 2.0f); sum += e[t]; }
    float inv = 1.0f / sum;
    #pragma unroll
    for (int t = 0; t < 8; ++t) {
      float wv = e[t] * inv;
      wsh[t] = wv;
      w_out[(size_t)b * 8 + t] = wv;
      w_ws[(size_t)b * 8 + t] = wv;
    }
    idx_out[b] = (float)amax;
  }
  __syncthreads();
  for (int d = tid; d < 1024; d += 256) {
    float acc = xr[d];
    #pragma unroll
    for (int t = 0; t < 8; ++t) acc += wsh[t] * b_down[t * 1024 + d];
    out_init[(size_t)b * 1024 + d] = acc;
  }
}

// ---------------- GEMM (r2-proven m97 structure) ----------------
// C[m][n] = sum_k A[m][k]*B[n][k], bf16 row-major. BM=128, BK=64.
// EPI 0: up, flat grid 8192 XCD-decoded: Ch = bf16(wcol*gelu(v+bias))
// EPI 2: cls, 2D grid: Cf = v + bias (guard n)
// EPI 3: down split-K, flat grid 1024 XCD-decoded: Cf[z] = v
template <int BN, int EPI>
__global__ __launch_bounds__(256, 2) void gemm_k(
    const unsigned short* __restrict__ A, int lda,
    const unsigned short* __restrict__ Bm, int ldb,
    int K,
    float* __restrict__ Cf, int ldc, int nvalid,
    unsigned short* __restrict__ Ch, int ldh,
    const float* __restrict__ bias,
    const float* __restrict__ wcol) {
  constexpr int FN = BN / 32;
  constexpr int AISS = 4;
  constexpr int BISS = BN / 32;

  __shared__ unsigned short As[128 * 64];
  __shared__ unsigned short Bs[BN * 64];

  int m0, n0;
  int k0beg = 0, k0end = K;
  if (EPI == 0) {
    // 8192 blocks: xcd = f&7 owns n-tiles [xcd*32, xcd*32+32), m fastest
    int f = blockIdx.x;
    int xcd = f & 7, i = f >> 3;
    n0 = (xcd * 32 + (i >> 5)) * 128;
    m0 = (i & 31) * 128;
  } else if (EPI == 3) {
    // 1024 blocks: z = xcd>>1 (A-slice per XCD-pair), 4 n per XCD, m fastest
    int f = blockIdx.x;
    int xcd = f & 7, i = f >> 3;
    int z = xcd >> 1;
    n0 = ((xcd & 1) * 4 + (i >> 5)) * 128;
    m0 = (i & 31) * 128;
    k0beg = z * 8192;
    k0end = k0beg + 8192;
    Cf += (size_t)z * 4194304;
  } else {
    m0 = blockIdx.y * 128;
    n0 = blockIdx.x * BN;
  }

  const int tid  = threadIdx.x;
  const int lane = tid & 63;
  const int wave = tid >> 6;
  const int lr = lane & 15;
  const int lg = lane >> 4;
  const int wm = (wave >> 1) * 64;
  const int wn = (wave & 1) * (BN / 2);
  const int sw = (lr & 7) << 4;

  f32x4 acc[4][FN];
  #pragma unroll
  for (int i = 0; i < 4; ++i)
    #pragma unroll
    for (int j = 0; j < FN; ++j)
      #pragma unroll
      for (int q = 0; q < 4; ++q) acc[i][j][q] = 0.f;

  const char* Ab = (const char*)As;
  const char* Bb = (const char*)Bs;
  const int Lw = wave * 1024 + lane * 16;

  for (int k0 = k0beg; k0 < k0end; k0 += 64) {
    #pragma unroll
    for (int it = 0; it < AISS; ++it) {
      int L = it * 4096 + Lw;
      int row = L >> 7;
      int cb = (L & 127) ^ ((row & 7) << 4);
      const unsigned short* g = A + (size_t)(m0 + row) * lda + k0 + (cb >> 1);
      gload16(g, (void*)((char*)As + it * 4096 + wave * 1024));
    }
    #pragma unroll
    for (int it = 0; it < BISS; ++it) {
      int L = it * 4096 + Lw;
      int row = L >> 7;
      int cb = (L & 127) ^ ((row & 7) << 4);
      const unsigned short* g = Bm + (size_t)(n0 + row) * ldb + k0 + (cb >> 1);
      gload16(g, (void*)((char*)Bs + it * 4096 + wave * 1024));
    }
    asm volatile("s_waitcnt vmcnt(0)" ::: "memory");
    __syncthreads();

    #pragma unroll
    for (int kk = 0; kk < 2; ++kk) {
      bf16x8 a[4], bfr[FN];
      const int cbase = (kk << 6) + (lg << 4);
      #pragma unroll
      for (int mi = 0; mi < 4; ++mi) {
        int r = wm + mi * 16 + lr;
        a[mi] = *(const bf16x8*)(Ab + (r << 7) + (cbase ^ sw));
      }
      #pragma unroll
      for (int ni = 0; ni < FN; ++ni) {
        int r = wn + ni * 16 + lr;
        bfr[ni] = *(const bf16x8*)(Bb + (r << 7) + (cbase ^ sw));
      }
      #pragma unroll
      for (int mi = 0; mi < 4; ++mi)
        #pragma unroll
        for (int ni = 0; ni < FN; ++ni)
          acc[mi][ni] = __builtin_amdgcn_mfma_f32_16x16x32_bf16(a[mi], bfr[ni], acc[mi][ni], 0, 0, 0);
    }
    __syncthreads();
  }

  // D frag mapping: col = lane&15, row = (lane>>4)*4 + r
  const int tblk = n0 >> 12;
  #pragma unroll
  for (int mi = 0; mi < 4; ++mi) {
    float wrow[4];
    if (EPI == 0) {
      #pragma unroll
      for (int r = 0; r < 4; ++r)
        wrow[r] = wcol[(size_t)(m0 + wm + mi * 16 + lg * 4 + r) * 8 + tblk];
    }
    #pragma unroll
    for (int ni = 0; ni < FN; ++ni) {
      int gn = n0 + wn + ni * 16 + lr;
      #pragma unroll
      for (int r = 0; r < 4; ++r) {
        int gm = m0 + wm + mi * 16 + lg * 4 + r;
        float v = acc[mi][ni][r];
        if (EPI == 0) {
          v += bias[gn];
          v = gelu_fast(v);
          v *= wrow[r];
          Ch[(size_t)gm * ldh + gn] = f2bf(v);
        } else if (EPI == 3) {
          Cf[(size_t)gm * ldc + gn] = v;
        } else {
          if (gn < nvalid) Cf[(size_t)gm * ldc + gn] = v + bias[gn];
        }
      }
    }
  }
}

// outb = bf16(out_init + p0+p1+p2+p3)
__global__ void combine_k(const float* __restrict__ init, const float* __restrict__ parts,
                          unsigned short* __restrict__ out) {
  int i = blockIdx.x * blockDim.x + threadIdx.x;
  float4 s = reinterpret_cast<const float4*>(init)[i];
  #pragma unroll
  for (int z = 0; z < 4; ++z) {
    float4 p = reinterpret_cast<const float4*>(parts + (size_t)z * 4194304)[i];
    s.x += p.x; s.y += p.y; s.z += p.z; s.w += p.w;
  }
  ushort4 o;
  o.x = f2bf(s.x); o.y = f2bf(s.y); o.z = f2bf(s.z); o.w = f2bf(s.w);
  reinterpret_cast<ushort4*>(out)[i] = o;
}

// ---------------- launch ----------------
extern "C" void kernel_launch(void* const* d_in, const int* in_sizes, int n_in,
                              void* d_out, int out_size, void* d_ws, size_t ws_size,
                              hipStream_t stream) {
  const float* x      = (const float*)d_in[0];
  const float* sig    = (const float*)d_in[1];
  const float* W_up   = (const float*)d_in[2];
  const float* b_up   = (const float*)d_in[3];
  const float* W_down = (const float*)d_in[4];
  const float* b_down = (const float*)d_in[5];
  const float* W_cls  = (const float*)d_in[6];
  const float* b_cls  = (const float*)d_in[7];

  float* outp    = (float*)d_out;
  float* logits  = outp;                       // 4096*1000
  float* idx_out = outp + 4096000;             // 4096
  float* w_out   = outp + 4096000 + 4096;      // 4096*8

  char* ws = (char*)d_ws;
  unsigned short* xb    = (unsigned short*)ws;  ws += 8388608;    // x bf16
  unsigned short* hsc   = (unsigned short*)ws;  ws += 268435456;  // h_sc bf16 (4096,32768)
  unsigned short* wupb  = (unsigned short*)ws;  ws += 67108864;   // W_up bf16 (32768,1024)
  unsigned short* wdnb  = (unsigned short*)ws;  ws += 67108864;   // W_dn bf16 (1024,32768)
  unsigned short* wclsb = (unsigned short*)ws;  ws += 2097152;    // W_cls bf16 padded
  unsigned short* outb  = (unsigned short*)ws;  ws += 8388608;    // out bf16
  float* out_init       = (float*)ws;           ws += 16777216;   // f32
  float* parts          = (float*)ws;           ws += 67108864;   // 4x split-K partials
  float* w_ws           = (float*)ws;           ws += 131072;     // weights (4096,8)

  dim3 blk(256);

  conv_bf16<<<dim3(4096), blk, 0, stream>>>(x, xb, 1048576);
  score_init<<<dim3(4096), blk, 0, stream>>>(x, sig, b_down, w_ws, out_init, w_out, idx_out);
  conv_bf16<<<dim3(32768), blk, 0, stream>>>(W_up, wupb, 8388608);
  conv_wdn<<<dim3(32768), blk, 0, stream>>>(W_down, wdnb);
  conv_wcls<<<dim3(1024), blk, 0, stream>>>(W_cls, wclsb);

  // up: h_sc = bf16( w * gelu(x @ Wup^T + b_up) ), M=4096 N=32768 K=1024
  gemm_k<128, 0><<<dim3(8192), blk, 0, stream>>>(
      xb, 1024, wupb, 1024, 1024,
      (float*)nullptr, 0, 0, hsc, 32768, b_up, w_ws);

  // down: parts[z] = h_sc @ Wdn^T over K-chunk z (z = xcd>>1)
  gemm_k<128, 3><<<dim3(1024), blk, 0, stream>>>(
      hsc, 32768, wdnb, 32768, 32768,
      parts, 1024, 0, (unsigned short*)nullptr, 0, (const float*)nullptr, (const float*)nullptr);

  combine_k<<<dim3(4096), blk, 0, stream>>>(out_init, parts, outb);

  // cls: logits = outb @ Wcls^T + b_cls
  gemm_k<64, 2><<<dim3(16, 32), blk, 0, stream>>>(
      outb, 1024, wclsb, 1024, 1024,
      logits, 1000, 1000, (unsigned short*)nullptr, 0, b_cls, (const float*)nullptr);
}

// Round 10
// 845.428 us; speedup vs baseline: 1.1087x; 1.1087x over previous
//
#include <hip/hip_runtime.h>
#include <stdint.h>

// SimpleTrixFFN round 10: r2's proven m97 GEMM with T4 counted-vmcnt dbuf,
// CORRECTED gate order (r9 post-mortem): per K-step
//   {B1; STAGE(u+1 -> slot^1); vmcnt(8); B2; COMP(u)}
// vmcnt is per-wave -> the barrier AFTER the counted wait is what guarantees
// all waves' stage(u) loads landed before any ds_read (r3/r5-proven order).
// B1 guarantees WAR safety for the STAGE overwrite (slot read at u-1).

typedef __attribute__((ext_vector_type(8))) __bf16 bf16x8;
typedef __attribute__((ext_vector_type(4))) float f32x4;

__device__ __forceinline__ unsigned short f2bf(float f) {
  union { float f; unsigned int u; } c; c.f = f;
  unsigned int u = c.u;
  u += 0x7FFFu + ((u >> 16) & 1u);   // round-to-nearest-even
  return (unsigned short)(u >> 16);
}

__device__ __forceinline__ float gelu_fast(float x) {
  float x2 = x * x;
  float p = __builtin_fmaf(0.044715f * x2, x, x);
  float e = __expf(-1.5957691216057308f * p);
  return x / (1.0f + e);
}

__device__ __forceinline__ void gload16(const void* g, void* l) {
  __builtin_amdgcn_global_load_lds((const __attribute__((address_space(1))) void*)g,
                                   (__attribute__((address_space(3))) void*)l,
                                   16, 0, 0);
}

// ---------------- conversion kernels ----------------
__global__ void conv_bf16(const float* __restrict__ in, unsigned short* __restrict__ out, int n4) {
  int i = blockIdx.x * blockDim.x + threadIdx.x;
  if (i >= n4) return;
  float4 v = reinterpret_cast<const float4*>(in)[i];
  ushort4 o;
  o.x = f2bf(v.x); o.y = f2bf(v.y); o.z = f2bf(v.z); o.w = f2bf(v.w);
  reinterpret_cast<ushort4*>(out)[i] = o;
}

// W_down (8,1024,4096)[t][d][h] -> bf16 (1024, 32768)[d][t*4096+h]
__global__ void conv_wdn(const float* __restrict__ in, unsigned short* __restrict__ out) {
  int i = blockIdx.x * blockDim.x + threadIdx.x;
  int idx = i * 4;
  int h = idx & 4095;
  int d = (idx >> 12) & 1023;
  int t = idx >> 22;
  float4 v = *reinterpret_cast<const float4*>(in + (size_t)(t * 1024 + d) * 4096 + h);
  ushort4 o;
  o.x = f2bf(v.x); o.y = f2bf(v.y); o.z = f2bf(v.z); o.w = f2bf(v.w);
  *reinterpret_cast<ushort4*>(out + (size_t)d * 32768 + t * 4096 + h) = o;
}

// W_cls (1000,1024) -> padded bf16 (1024,1024)
__global__ void conv_wcls(const float* __restrict__ in, unsigned short* __restrict__ out) {
  int i = blockIdx.x * blockDim.x + threadIdx.x;
  int idx = i * 4;
  int row = idx >> 10;
  float4 v = make_float4(0.f, 0.f, 0.f, 0.f);
  if (row < 1000) v = *reinterpret_cast<const float4*>(in + row * 1024 + (idx & 1023));
  ushort4 o;
  o.x = f2bf(v.x); o.y = f2bf(v.y); o.z = f2bf(v.z); o.w = f2bf(v.w);
  reinterpret_cast<ushort4*>(out)[i] = o;
}

// ---------------- routing ----------------
__global__ void score_init(const float* __restrict__ x, const float* __restrict__ sig,
                           const float* __restrict__ b_down,
                           float* __restrict__ w_ws, float* __restrict__ out_init,
                           float* __restrict__ w_out, float* __restrict__ idx_out) {
  const int b = blockIdx.x;
  const int tid = threadIdx.x;
  const int lane = tid & 63;
  const int wave = tid >> 6;
  const float* xr = x + (size_t)b * 1024;

  float p[8];
  #pragma unroll
  for (int t = 0; t < 8; ++t) p[t] = 0.f;
  for (int k = tid; k < 1024; k += 256) {
    float xv = xr[k];
    #pragma unroll
    for (int t = 0; t < 8; ++t) p[t] += xv * sig[t * 1024 + k];
  }
  #pragma unroll
  for (int t = 0; t < 8; ++t) {
    #pragma unroll
    for (int off = 32; off > 0; off >>= 1) p[t] += __shfl_down(p[t], off);
  }
  __shared__ float red[4][8];
  __shared__ float wsh[8];
  if (lane == 0) {
    #pragma unroll
    for (int t = 0; t < 8; ++t) red[wave][t] = p[t];
  }
  __syncthreads();
  if (tid == 0) {
    float s[8];
    #pragma unroll
    for (int t = 0; t < 8; ++t) s[t] = red[0][t] + red[1][t] + red[2][t] + red[3][t];
    int amax = 0; float mx = s[0];
    #pragma unroll
    for (int t = 1; t < 8; ++t) { if (s[t] > mx) { mx = s[t]; amax = t; } }
    float e[8], sum = 0.f;
    #pragma unroll
    for (int t = 0; t < 8; ++t) { e[t] = expf((s[t] - mx) * 2.0f); sum += e[t]; }
    float inv = 1.0f / sum;
    #pragma unroll
    for (int t = 0; t < 8; ++t) {
      float wv = e[t] * inv;
      wsh[t] = wv;
      w_out[(size_t)b * 8 + t] = wv;
      w_ws[(size_t)b * 8 + t] = wv;
    }
    idx_out[b] = (float)amax;
  }
  __syncthreads();
  for (int d = tid; d < 1024; d += 256) {
    float acc = xr[d];
    #pragma unroll
    for (int t = 0; t < 8; ++t) acc += wsh[t] * b_down[t * 1024 + d];
    out_init[(size_t)b * 1024 + d] = acc;
  }
}

// ---------------- GEMM: m97 structure + T4 counted-vmcnt dbuf ----------------
// C[m][n] = sum_k A[m][k]*B[n][k], bf16 row-major. BM=128, BK=64.
// EPI 0: up (grid 256n x 32m): Ch = bf16(wcol * gelu(v + bias))
// EPI 2: cls (grid 16n x 32m): Cf = v + bias (guard n < nvalid)
// EPI 3: down split-K (grid 8n x 32m x 4z): Cf[z] = v
template <int BN, int EPI>
__global__ __launch_bounds__(256, 2) void gemm_k(
    const unsigned short* __restrict__ A, int lda,
    const unsigned short* __restrict__ Bm, int ldb,
    int K,
    float* __restrict__ Cf, int ldc, int nvalid,
    unsigned short* __restrict__ Ch, int ldh,
    const float* __restrict__ bias,
    const float* __restrict__ wcol) {
  constexpr int FN = BN / 32;
  constexpr int BISS = BN / 32;          // B stage iters (4096B each)
  constexpr int BSLOT = BN * 128;        // B slot bytes

  __shared__ char lds[32768 + 2 * BSLOT];

  if (EPI == 3) {
    size_t kz = (size_t)blockIdx.z * K;
    A += kz;
    Bm += kz;
    Cf += (size_t)blockIdx.z * 4194304;
  }

  const int tid  = threadIdx.x;
  const int lane = tid & 63;
  const int wave = tid >> 6;
  const int m0 = blockIdx.y * 128;
  const int n0 = blockIdx.x * BN;
  const int lr = lane & 15;
  const int lg = lane >> 4;
  const int wm = (wave >> 1) * 64;
  const int wn = (wave & 1) * (BN / 2);
  const int sw = (lr & 7) << 4;

  f32x4 acc[4][FN];
  #pragma unroll
  for (int i = 0; i < 4; ++i)
    #pragma unroll
    for (int j = 0; j < FN; ++j)
      #pragma unroll
      for (int q = 0; q < 4; ++q) acc[i][j][q] = 0.f;

  const int Lw = wave * 1024 + lane * 16;

#define STAGE(k0_, s_)                                                    \
  {                                                                       \
    _Pragma("unroll")                                                     \
    for (int it = 0; it < 4; ++it) {                                      \
      int L = it * 4096 + Lw;                                             \
      int row = L >> 7;                                                   \
      int cb = (L & 127) ^ ((row & 7) << 4);                              \
      gload16(A + (size_t)(m0 + row) * lda + (k0_) + (cb >> 1),           \
              lds + (s_) * 16384 + it * 4096 + wave * 1024);              \
    }                                                                     \
    _Pragma("unroll")                                                     \
    for (int it = 0; it < BISS; ++it) {                                   \
      int L = it * 4096 + Lw;                                             \
      int row = L >> 7;                                                   \
      int cb = (L & 127) ^ ((row & 7) << 4);                              \
      gload16(Bm + (size_t)(n0 + row) * ldb + (k0_) + (cb >> 1),          \
              lds + 32768 + (s_) * BSLOT + it * 4096 + wave * 1024);      \
    }                                                                     \
  }

#define COMP(s_)                                                          \
  {                                                                       \
    const char* Ab_ = lds + (s_) * 16384;                                 \
    const char* Bb_ = lds + 32768 + (s_) * BSLOT;                         \
    _Pragma("unroll")                                                     \
    for (int kk = 0; kk < 2; ++kk) {                                      \
      bf16x8 a[4], bfr[FN];                                               \
      const int cbase = (kk << 6) + (lg << 4);                            \
      _Pragma("unroll")                                                   \
      for (int mi = 0; mi < 4; ++mi) {                                    \
        int r = wm + mi * 16 + lr;                                        \
        a[mi] = *(const bf16x8*)(Ab_ + (r << 7) + (cbase ^ sw));          \
      }                                                                   \
      _Pragma("unroll")                                                   \
      for (int ni = 0; ni < FN; ++ni) {                                   \
        int r = wn + ni * 16 + lr;                                        \
        bfr[ni] = *(const bf16x8*)(Bb_ + (r << 7) + (cbase ^ sw));        \
      }                                                                   \
      _Pragma("unroll")                                                   \
      for (int mi = 0; mi < 4; ++mi)                                      \
        _Pragma("unroll")                                                 \
        for (int ni = 0; ni < FN; ++ni)                                   \
          acc[mi][ni] = __builtin_amdgcn_mfma_f32_16x16x32_bf16(          \
              a[mi], bfr[ni], acc[mi][ni], 0, 0, 0);                      \
    }                                                                     \
  }

#define VMW                                                               \
  if constexpr (BN == 128) {                                              \
    asm volatile("s_waitcnt vmcnt(8)" ::: "memory");                      \
  } else {                                                                \
    asm volatile("s_waitcnt vmcnt(6)" ::: "memory");                      \
  }
#define VM0  asm volatile("s_waitcnt vmcnt(0)" ::: "memory");
#define BARR asm volatile("s_barrier" ::: "memory");

  // prologue: stage tile 0 into slot 0
  STAGE(0, 0)
  int s = 0;
  int k0 = 0;
  // main: {B1 (WAR: COMP(u-1) readers done); STAGE(u+1); VMW (own stage(u)
  // retired); B2 (ALL waves' stage(u) landed); COMP(u)}
  for (; k0 + 64 < K; k0 += 64) {
    BARR
    STAGE(k0 + 64, s ^ 1)
    VMW
    BARR
    COMP(s)
    s ^= 1;
  }
  // tail: last tile (only stage(last) in flight)
  BARR
  VM0
  BARR
  COMP(s)

#undef STAGE
#undef COMP
#undef VMW
#undef VM0
#undef BARR

  // epilogue: D frag mapping col = lane&15, row = (lane>>4)*4 + r
  const int tblk = n0 >> 12;
  #pragma unroll
  for (int mi = 0; mi < 4; ++mi) {
    float wrow[4];
    if (EPI == 0) {
      #pragma unroll
      for (int r = 0; r < 4; ++r)
        wrow[r] = wcol[(size_t)(m0 + wm + mi * 16 + lg * 4 + r) * 8 + tblk];
    }
    #pragma unroll
    for (int ni = 0; ni < FN; ++ni) {
      int gn = n0 + wn + ni * 16 + lr;
      #pragma unroll
      for (int r = 0; r < 4; ++r) {
        int gm = m0 + wm + mi * 16 + lg * 4 + r;
        float v = acc[mi][ni][r];
        if (EPI == 0) {
          v += bias[gn];
          v = gelu_fast(v);
          v *= wrow[r];
          Ch[(size_t)gm * ldh + gn] = f2bf(v);
        } else if (EPI == 3) {
          Cf[(size_t)gm * ldc + gn] = v;
        } else {
          if (gn < nvalid) Cf[(size_t)gm * ldc + gn] = v + bias[gn];
        }
      }
    }
  }
}

// outb = bf16(out_init + p0+p1+p2+p3)
__global__ void combine_k(const float* __restrict__ init, const float* __restrict__ parts,
                          unsigned short* __restrict__ out) {
  int i = blockIdx.x * blockDim.x + threadIdx.x;
  float4 s = reinterpret_cast<const float4*>(init)[i];
  #pragma unroll
  for (int z = 0; z < 4; ++z) {
    float4 p = reinterpret_cast<const float4*>(parts + (size_t)z * 4194304)[i];
    s.x += p.x; s.y += p.y; s.z += p.z; s.w += p.w;
  }
  ushort4 o;
  o.x = f2bf(s.x); o.y = f2bf(s.y); o.z = f2bf(s.z); o.w = f2bf(s.w);
  reinterpret_cast<ushort4*>(out)[i] = o;
}

// ---------------- launch ----------------
extern "C" void kernel_launch(void* const* d_in, const int* in_sizes, int n_in,
                              void* d_out, int out_size, void* d_ws, size_t ws_size,
                              hipStream_t stream) {
  const float* x      = (const float*)d_in[0];
  const float* sig    = (const float*)d_in[1];
  const float* W_up   = (const float*)d_in[2];
  const float* b_up   = (const float*)d_in[3];
  const float* W_down = (const float*)d_in[4];
  const float* b_down = (const float*)d_in[5];
  const float* W_cls  = (const float*)d_in[6];
  const float* b_cls  = (const float*)d_in[7];

  float* outp    = (float*)d_out;
  float* logits  = outp;                       // 4096*1000
  float* idx_out = outp + 4096000;             // 4096
  float* w_out   = outp + 4096000 + 4096;      // 4096*8

  char* ws = (char*)d_ws;
  unsigned short* xb    = (unsigned short*)ws;  ws += 8388608;    // x bf16
  unsigned short* hsc   = (unsigned short*)ws;  ws += 268435456;  // h_sc bf16 (4096,32768)
  unsigned short* wupb  = (unsigned short*)ws;  ws += 67108864;   // W_up bf16 (32768,1024)
  unsigned short* wdnb  = (unsigned short*)ws;  ws += 67108864;   // W_dn bf16 (1024,32768)
  unsigned short* wclsb = (unsigned short*)ws;  ws += 2097152;    // W_cls bf16 padded
  unsigned short* outb  = (unsigned short*)ws;  ws += 8388608;    // out bf16
  float* out_init       = (float*)ws;           ws += 16777216;   // f32
  float* parts          = (float*)ws;           ws += 67108864;   // 4x split-K partials
  float* w_ws           = (float*)ws;           ws += 131072;     // weights (4096,8)

  dim3 blk(256);

  conv_bf16<<<dim3(4096), blk, 0, stream>>>(x, xb, 1048576);
  score_init<<<dim3(4096), blk, 0, stream>>>(x, sig, b_down, w_ws, out_init, w_out, idx_out);
  conv_bf16<<<dim3(32768), blk, 0, stream>>>(W_up, wupb, 8388608);
  conv_wdn<<<dim3(32768), blk, 0, stream>>>(W_down, wdnb);
  conv_wcls<<<dim3(1024), blk, 0, stream>>>(W_cls, wclsb);

  // up: h_sc = bf16( w * gelu(x @ Wup^T + b_up) ), M=4096 N=32768 K=1024
  gemm_k<128, 0><<<dim3(256, 32), blk, 0, stream>>>(
      xb, 1024, wupb, 1024, 1024,
      (float*)nullptr, 0, 0, hsc, 32768, b_up, w_ws);

  // down: parts[z] = h_sc @ Wdn^T over K-chunk z, M=4096 N=1024 K=32768/4
  gemm_k<128, 3><<<dim3(8, 32, 4), blk, 0, stream>>>(
      hsc, 32768, wdnb, 32768, 8192,
      parts, 1024, 0, (unsigned short*)nullptr, 0, (const float*)nullptr, (const float*)nullptr);

  combine_k<<<dim3(4096), blk, 0, stream>>>(out_init, parts, outb);

  // cls: logits = outb @ Wcls^T + b_cls
  gemm_k<64, 2><<<dim3(16, 32), blk, 0, stream>>>(
      outb, 1024, wclsb, 1024, 1024,
      logits, 1000, 1000, (unsigned short*)nullptr, 0, b_cls, (const float*)nullptr);
}